// Round 13
// baseline (254.651 us; speedup 1.0000x reference)
//
#include <hip/hip_runtime.h>
#include <hip/hip_bf16.h>
#include <hip/hip_fp16.h>

// Bahdanau location-sensitive attention, fused f16-MFMA implementation.
// R13: R12 (4x256-thr blocks/CU, Af f16, gload_lds) +
//      (a) k_main BK=32 double-buffered prefetch (T3-minimum 2-phase) at
//          unchanged 34 KB LDS -> still 4 blocks/CU; super-row LDS layout
//          (64 SR x 128B, phys slot = slot ^ (SR&7), 2-way free);
//      (b) ctx_part vectorized f16x8 reads of Af (was 4 scalar u16/row);
//      (c) prep_b2 int4 writes; cpart aliases spart region (ws bounded).
// B=32 T=1536 H=1024 CTX=1024 CONV_OUT=32

constexpr int kB = 32, kT = 1536, kH = 1024, kC = 1024, kCO = 32;
constexpr int kM = kB * kT;      // 49152
constexpr int kKp = 1088;        // padded K: 1024 enc | 32 loc | 32 zero

typedef _Float16 f16;
typedef _Float16 f16x8 __attribute__((ext_vector_type(8)));
typedef float f32x4 __attribute__((ext_vector_type(4)));

// ---- ws layout (bytes) ----
constexpr size_t W2_A    = 0;                                    // kM*kKp f16 = 106.95 MB
constexpr size_t W2_B    = W2_A + (size_t)kM * kKp * 2;          // kC*kKp f16 = 2.23 MB
constexpr size_t W2_ADD  = W2_B + (size_t)kC * kKp * 2;          // kB*kC f32
constexpr size_t W2_SCR  = W2_ADD + (size_t)kB * kC * 4;         // spart (8*kM f32) / cpart (16*kB*kH f32) aliased
// total ~111.4 MB (< R12's proven 111.9 MB footprint)

__device__ __forceinline__ void gload16(const void* g, void* l) {
    __builtin_amdgcn_global_load_lds(
        (const __attribute__((address_space(1))) void*)g,
        (__attribute__((address_space(3))) void*)l, 16, 0, 0);
}

// ---------------------------------------------------------------- cvt enc -> Af cols 0..1023 (sequential HBM)
__global__ void k_cvt(const float* __restrict__ enc, f16* __restrict__ Af) {
    int gid = blockIdx.x * 256 + threadIdx.x;       // < kM*kH/8
    int row = gid >> 7, c8 = gid & 127;
    const float* src = enc + (size_t)row * kH + c8 * 8;
    float4 e0 = *(const float4*)src;
    float4 e1 = *(const float4*)(src + 4);
    union { f16 h[8]; int4 q; } u;
    u.h[0] = (f16)e0.x; u.h[1] = (f16)e0.y; u.h[2] = (f16)e0.z; u.h[3] = (f16)e0.w;
    u.h[4] = (f16)e1.x; u.h[5] = (f16)e1.y; u.h[6] = (f16)e1.z; u.h[7] = (f16)e1.w;
    *(int4*)(Af + (size_t)row * kKp + c8 * 8) = u.q;
}

// ---------------------------------------------------------------- conv1d -> Af cols 1024..1087
__global__ void k_loc(const float* __restrict__ la, const float* __restrict__ cw,
                      const float* __restrict__ cb, f16* __restrict__ Af) {
    int m = blockIdx.x * 256 + threadIdx.x;          // < kM
    int b = m / kT, t = m - b * kT;
    float x0 = (t > 0)      ? la[(size_t)b * kT + t - 1] : 0.f;
    float x1 = la[(size_t)b * kT + t];
    float x2 = (t < kT - 1) ? la[(size_t)b * kT + t + 1] : 0.f;
    union { f16 h[32]; int4 q[4]; } u;
#pragma unroll
    for (int k = 0; k < 32; ++k)
        u.h[k] = (f16)(cw[k * 3] * x0 + cw[k * 3 + 1] * x1 + cw[k * 3 + 2] * x2 + cb[k]);
    int4* dst = (int4*)(Af + (size_t)m * kKp + kH);
    dst[0] = u.q[0]; dst[1] = u.q[1]; dst[2] = u.q[2]; dst[3] = u.q[3];
    int4 z = {0, 0, 0, 0};
    dst[4] = z; dst[5] = z; dst[6] = z; dst[7] = z;   // zero pad 1056..1087
}

// ---------------------------------------------------------------- B pack [kC][1088] f16 (vectorized)
__global__ void k_prep_b2(const float* __restrict__ V, const float* __restrict__ U,
                          f16* __restrict__ Bf) {
    int c = blockIdx.x, k8 = threadIdx.x;            // active k8 < 136
    if (k8 >= 136) return;
    union { f16 h[8]; int4 q; } u;
    if (k8 < 128) {
        const float* src = V + (size_t)c * kH + k8 * 8;
        float4 a = *(const float4*)src, b = *(const float4*)(src + 4);
        u.h[0] = (f16)a.x; u.h[1] = (f16)a.y; u.h[2] = (f16)a.z; u.h[3] = (f16)a.w;
        u.h[4] = (f16)b.x; u.h[5] = (f16)b.y; u.h[6] = (f16)b.z; u.h[7] = (f16)b.w;
    } else if (k8 < 132) {
        const float* src = U + (size_t)c * kCO + (k8 - 128) * 8;
        float4 a = *(const float4*)src, b = *(const float4*)(src + 4);
        u.h[0] = (f16)a.x; u.h[1] = (f16)a.y; u.h[2] = (f16)a.z; u.h[3] = (f16)a.w;
        u.h[4] = (f16)b.x; u.h[5] = (f16)b.y; u.h[6] = (f16)b.z; u.h[7] = (f16)b.w;
    } else {
        u.q = (int4){0, 0, 0, 0};
    }
    *(int4*)(Bf + (size_t)c * kKp + k8 * 8) = u.q;
}

// ---------------------------------------------------------------- prep add = dec@W^T + bias
__global__ void k_prep_add(const float* __restrict__ dec, const float* __restrict__ W,
                           const float* __restrict__ bias, float* __restrict__ add) {
    __shared__ float dl[kH];
    int bb = blockIdx.x >> 2;
    int cc = (blockIdx.x & 3) * 256 + threadIdx.x;
    *(float4*)&dl[threadIdx.x * 4] = *(const float4*)&dec[(size_t)bb * kH + threadIdx.x * 4];
    __syncthreads();
    float acc = bias[cc];
    const float* wr = W + (size_t)cc * kH;
    for (int h = 0; h < kH; h += 4) {
        float4 wv = *(const float4*)&wr[h];
        acc += wv.x * dl[h] + wv.y * dl[h + 1] + wv.z * dl[h + 2] + wv.w * dl[h + 3];
    }
    add[(size_t)bb * kC + cc] = acc;
}

// ---------------------------------------------------------------- fused main GEMM
// Tile 128(M) x 128(N), BK=32, 256 thr = 4 waves (2M x 2N), per-wave 64x64.
// LDS (34816 B), double-buffered: buf c @ c*16384: As 8 KB + Bs 8 KB.
//   Layout per operand: 64 super-rows x 128 B; SR R = rows {2R, 2R+1};
//   slot s = (row&1)*4 + kchunk(16B); phys = s ^ (R&7)  -> 2-way free on
//   ds_read_b128 and linear gload writes (source pre-permuted).
// add_l @32768, w_l @33280, sred @33792. 4 blocks/CU; per K-step:
//   issue next-tile gloads -> ds_read+MFMA current -> syncthreads (1 drain).
__launch_bounds__(256, 4)
__global__ void k_main(const f16* __restrict__ Ag, const f16* __restrict__ Bg,
                       const float* __restrict__ add, const float* __restrict__ wvec,
                       float* __restrict__ spart) {
    __shared__ __align__(16) char smem[34816];
    float* add_l = (float*)(smem + 32768);
    float* w_l   = (float*)(smem + 33280);
    float (*sred)[64][2] = (float (*)[64][2])(smem + 33792);

    const int tid = threadIdx.x, lane = tid & 63, wave = tid >> 6;
    const int wm = wave >> 1, wn = wave & 1;
    // bijective XCD swizzle: 3072 blocks = 8 XCDs x 384; nt fastest (8 per A strip)
    const int raw = blockIdx.x;
    const int lin = (raw & 7) * 384 + (raw >> 3);
    const int mt = lin >> 3, nt = lin & 7;
    const int m0 = mt * 128, n0 = nt * 128;
    const int bb = m0 / kT;                          // 128 | 1536

    if (tid < 128) {
        add_l[tid] = add[(size_t)bb * kC + n0 + tid];
        w_l[tid]   = wvec[n0 + tid];
    }

    f32x4 acc[4][4];
#pragma unroll
    for (int i = 0; i < 4; ++i)
#pragma unroll
        for (int j = 0; j < 4; ++j) acc[i][j] = (f32x4){0.f, 0.f, 0.f, 0.f};

    // staging sources: instr j covers SRs wave*16 + j*8 .. +8 (16 rows, 1 KB).
    // lane l -> SR = +l>>3, phys slot = l&7; src slot = phys ^ (SR&7) = (l&7)^(l>>3).
    const int SRl  = lane >> 3;
    const int slot = (lane & 7) ^ SRl;
    const int scol = (slot & 3) * 8;                 // f16 col of 16B chunk
    const int sr0  = 2 * (wave * 16 + SRl) + (slot >> 2);       // instr 0 row
    const int sr1  = 2 * (wave * 16 + 8 + SRl) + (slot >> 2);   // instr 1 row
    const f16* aS0 = Ag + (size_t)(m0 + sr0) * kKp + scol;
    const f16* aS1 = Ag + (size_t)(m0 + sr1) * kKp + scol;
    const f16* bS0 = Bg + (size_t)(n0 + sr0) * kKp + scol;
    const f16* bS1 = Bg + (size_t)(n0 + sr1) * kKp + scol;
    const unsigned aDst = wave * 2048u;              // A region: SR*128
    const unsigned bDst = 8192u + wave * 2048u;      // B region

    // ds_read bases: row = w*64 + i*16 + rl -> SR = w*32 + i*8 + (rl>>1);
    // phys = ((rl&1)*4 + g) ^ (rl>>1); subtile i adds i*1024 bytes.
    const int g = lane >> 4, rl = lane & 15;
    const unsigned phys = (unsigned)((((rl & 1) << 2) + g) ^ (rl >> 1));
    const unsigned aRd = (unsigned)((wm * 32 + (rl >> 1)) * 128) + phys * 16u;
    const unsigned bRd = 8192u + (unsigned)((wn * 32 + (rl >> 1)) * 128) + phys * 16u;

    // ---- prologue: stage K-step 0 into buf0
    gload16(aS0, smem + aDst);
    gload16(aS1, smem + aDst + 1024);
    gload16(bS0, smem + bDst);
    gload16(bS1, smem + bDst + 1024);
    __syncthreads();

    unsigned bufC = 0u;
    for (int t = 0; t < 34; ++t) {                   // 34 uniform K-steps (incl. loc + pad)
        if (t < 33) {                                // issue next-tile stages first (overlap)
            const int o = (t + 1) * 32;
            const unsigned bn = bufC ^ 16384u;
            gload16(aS0 + o, smem + bn + aDst);
            gload16(aS1 + o, smem + bn + aDst + 1024);
            gload16(bS0 + o, smem + bn + bDst);
            gload16(bS1 + o, smem + bn + bDst + 1024);
        }
        f16x8 af[4], bfv[4];
#pragma unroll
        for (int ni = 0; ni < 4; ++ni)
            bfv[ni] = *(const f16x8*)(smem + bufC + bRd + ni * 1024);
#pragma unroll
        for (int mi = 0; mi < 4; ++mi)
            af[mi] = *(const f16x8*)(smem + bufC + aRd + mi * 1024);
        __builtin_amdgcn_s_setprio(1);
#pragma unroll
        for (int mi = 0; mi < 4; ++mi)
#pragma unroll
            for (int ni = 0; ni < 4; ++ni)
                acc[mi][ni] = __builtin_amdgcn_mfma_f32_16x16x32_f16(af[mi], bfv[ni], acc[mi][ni], 0, 0, 0);
        __builtin_amdgcn_s_setprio(0);
        __syncthreads();                             // drains this step's gloads once
        bufC ^= 16384u;
    }

    // ---- epilogue: e = tanh(acc + add[c]); partial score = sum_c e*w[c]
#pragma unroll
    for (int mi = 0; mi < 4; ++mi) {
#pragma unroll
        for (int i = 0; i < 4; ++i) {
            float p = 0.f;
#pragma unroll
            for (int ni = 0; ni < 4; ++ni) {
                int cl = wn * 64 + ni * 16 + rl;
                float e = tanhf(acc[mi][ni][i] + add_l[cl]);
                p += e * w_l[cl];
            }
            p += __shfl_xor(p, 1);
            p += __shfl_xor(p, 2);
            p += __shfl_xor(p, 4);
            p += __shfl_xor(p, 8);
            if (rl == 0) sred[wm][mi * 16 + g * 4 + i][wn] = p;
        }
    }
    __syncthreads();
    if (tid < 128) {
        int r = tid & 63, w2 = tid >> 6;
        float s = sred[w2][r][0] + sred[w2][r][1];
        spart[(size_t)nt * kM + m0 + tid] = s;
    }
}

// ---------------------------------------------------------------- softmax over T (8 partials)
__global__ void k_softmax(const float* __restrict__ spart, float* __restrict__ out_align) {
    __shared__ float red[256];
    int b = blockIdx.x, tid = threadIdx.x;
    float v[6];
    float mx = -1e30f;
#pragma unroll
    for (int i = 0; i < 6; ++i) {
        size_t idx = (size_t)b * kT + tid + i * 256;
        float s = 0.f;
#pragma unroll
        for (int p = 0; p < 8; ++p) s += spart[(size_t)p * kM + idx];
        v[i] = s; mx = fmaxf(mx, s);
    }
    red[tid] = mx; __syncthreads();
    for (int o = 128; o > 0; o >>= 1) { if (tid < o) red[tid] = fmaxf(red[tid], red[tid + o]); __syncthreads(); }
    mx = red[0]; __syncthreads();
    float sum = 0.f;
#pragma unroll
    for (int i = 0; i < 6; ++i) { v[i] = expf(v[i] - mx); sum += v[i]; }
    red[tid] = sum; __syncthreads();
    for (int o = 128; o > 0; o >>= 1) { if (tid < o) red[tid] += red[tid + o]; __syncthreads(); }
    float inv = 1.f / red[0];
#pragma unroll
    for (int i = 0; i < 6; ++i)
        out_align[(size_t)b * kT + tid + i * 256] = v[i] * inv;
}

// ---------------------------------------------------------------- context (vectorized Af f16x8 reads)
__global__ void k_ctx_part(const f16* __restrict__ Af, const float* __restrict__ align,
                           float* __restrict__ cpart) {
    __shared__ float al[192];
    int ci = blockIdx.x, b = blockIdx.y, tid = threadIdx.x;
    if (tid < 192) al[tid] = align[(size_t)b * kT + ci * 192 + tid];
    __syncthreads();
    const int half = tid >> 7;                        // rows [half*96, +96)
    const int c8 = tid & 127;                         // 8 H-cols
    float a0 = 0.f, a1 = 0.f, a2 = 0.f, a3 = 0.f, a4 = 0.f, a5 = 0.f, a6 = 0.f, a7 = 0.f;
    const f16* ep = Af + ((size_t)b * kT + ci * 192 + half * 96) * kKp + c8 * 8;
    for (int t = 0; t < 96; ++t) {
        float a = al[half * 96 + t];
        f16x8 e = *(const f16x8*)(ep + (size_t)t * kKp);
        a0 += a * (float)e[0]; a1 += a * (float)e[1]; a2 += a * (float)e[2]; a3 += a * (float)e[3];
        a4 += a * (float)e[4]; a5 += a * (float)e[5]; a6 += a * (float)e[6]; a7 += a * (float)e[7];
    }
    size_t base = ((size_t)(ci * 2 + half) * kB + b) * kH + (size_t)c8 * 8;
    *(float4*)&cpart[base]     = (float4){a0, a1, a2, a3};
    *(float4*)&cpart[base + 4] = (float4){a4, a5, a6, a7};
}

__global__ void k_ctx_red(const float* __restrict__ cpart, float* __restrict__ out_ctx) {
    int idx = blockIdx.x * 256 + threadIdx.x;
    float s = 0.f;
#pragma unroll
    for (int p = 0; p < 16; ++p) s += cpart[(size_t)p * kB * kH + idx];
    out_ctx[idx] = s;
}

// ---------------------------------------------------------------- launch
extern "C" void kernel_launch(void* const* d_in, const int* in_sizes, int n_in,
                              void* d_out, int out_size, void* d_ws, size_t ws_size,
                              hipStream_t stream) {
    const float* dec  = (const float*)d_in[0];
    const float* enc  = (const float*)d_in[1];
    const float* la   = (const float*)d_in[2];
    const float* W    = (const float*)d_in[3];
    const float* V    = (const float*)d_in[4];
    const float* U    = (const float*)d_in[5];
    const float* bias = (const float*)d_in[6];
    const float* wv   = (const float*)d_in[7];
    const float* cw   = (const float*)d_in[8];
    const float* cb   = (const float*)d_in[9];

    char* ws = (char*)d_ws;
    f16* Af      = (f16*)(ws + W2_A);
    f16* Bf      = (f16*)(ws + W2_B);
    float* add   = (float*)(ws + W2_ADD);
    float* spart = (float*)(ws + W2_SCR);            // 8*kM f32
    float* cpart = (float*)(ws + W2_SCR);            // 16*kB*kH f32 (after softmax, spart dead)

    float* out_ctx   = (float*)d_out;            // (B,H)
    float* out_align = (float*)d_out + kB * kH;  // (B,T)

    hipLaunchKernelGGL(k_prep_b2,  dim3(kC),             dim3(256), 0, stream, V, U, Bf);
    hipLaunchKernelGGL(k_loc,      dim3(kM / 256),       dim3(256), 0, stream, la, cw, cb, Af);
    hipLaunchKernelGGL(k_cvt,      dim3(kM * kH / 8 / 256), dim3(256), 0, stream, enc, Af);
    hipLaunchKernelGGL(k_prep_add, dim3(kB * 4),         dim3(256), 0, stream, dec, W, bias, add);
    hipLaunchKernelGGL(k_main,     dim3((kM / 128) * 8), dim3(256), 0, stream, Af, Bf, add, wv, spart);
    hipLaunchKernelGGL(k_softmax,  dim3(kB),             dim3(256), 0, stream, spart, out_align);
    hipLaunchKernelGGL(k_ctx_part, dim3(8, kB),          dim3(256), 0, stream, Af, out_align, cpart);
    hipLaunchKernelGGL(k_ctx_red,  dim3(kB * kH / 256),  dim3(256), 0, stream, cpart, out_ctx);
}